// Round 7
// baseline (454.511 us; speedup 1.0000x reference)
//
#include <hip/hip_runtime.h>
#include <math.h>

#define NE 8      // experts
#define ND 512    // features
#define NH 2048   // hidden
#define NT 2048   // tokens = B*S

typedef __attribute__((ext_vector_type(8)))  short short8;   // 8 bf16 = 4 VGPRs
typedef __attribute__((ext_vector_type(16))) float f32x16;   // 32x32 MFMA accumulator

#define GLL(g, d) __builtin_amdgcn_global_load_lds( \
    (const __attribute__((address_space(1))) void*)(g), \
    (__attribute__((address_space(3))) void*)(d), 16, 0, 0)

__device__ __forceinline__ unsigned short f2bf(float x) {
    unsigned int u = __builtin_bit_cast(unsigned int, x);
    u += 0x7FFFu + ((u >> 16) & 1u);            // round-to-nearest-even
    return (unsigned short)(u >> 16);
}

__device__ __forceinline__ short8 neg8(short8 v) {
    int4 u = __builtin_bit_cast(int4, v);
    u.x ^= 0x80008000; u.y ^= 0x80008000; u.z ^= 0x80008000; u.w ^= 0x80008000;
    return __builtin_bit_cast(short8, u);
}

__device__ __forceinline__ short8 lds8(const unsigned short* p) {
    return *(const short8*)p;
}
__device__ __forceinline__ short8 glb8(const unsigned short* p) {
    return *(const short8*)p;
}

// ---------------- gating (fp32, exact argmax) + fused x->bf16 ----------------
__global__ __launch_bounds__(256) void gate_kernel(
    const float* __restrict__ xr, const float* __restrict__ xi,
    const float* __restrict__ gW, const float* __restrict__ gb,
    float* __restrict__ gate_w,
    int* __restrict__ counts, int* __restrict__ tok_list,
    unsigned short* __restrict__ xbr, unsigned short* __restrict__ xbi)
{
    int t = blockIdx.x;
    int tid = threadIdx.x;
    const float* xrt = xr + (size_t)t * ND;
    const float* xit = xi + (size_t)t * ND;
    unsigned short* obr = xbr + (size_t)t * ND;
    unsigned short* obi = xbi + (size_t)t * ND;

    float acc[NE] = {0,0,0,0,0,0,0,0};
    for (int r = tid; r < 2 * ND; r += 256) {
        int d = r & (ND - 1);
        float a = xrt[d], b = xit[d];
        float v;
        if (r < ND) {
            v = sqrtf(a * a + b * b);
            obr[d] = f2bf(a);            // fused convx
            obi[d] = f2bf(b);
        } else {
            v = atan2f(b, a);
        }
        const float4* g = (const float4*)(gW + (size_t)r * NE);
        float4 g0 = g[0], g1 = g[1];
        acc[0] += v * g0.x; acc[1] += v * g0.y; acc[2] += v * g0.z; acc[3] += v * g0.w;
        acc[4] += v * g1.x; acc[5] += v * g1.y; acc[6] += v * g1.z; acc[7] += v * g1.w;
    }
    #pragma unroll
    for (int e = 0; e < NE; e++) {
        for (int off = 32; off > 0; off >>= 1)
            acc[e] += __shfl_down(acc[e], off, 64);
    }
    __shared__ float part[4][NE];
    int wave = tid >> 6, lane = tid & 63;
    if (lane == 0) {
        #pragma unroll
        for (int e = 0; e < NE; e++) part[wave][e] = acc[e];
    }
    __syncthreads();
    if (tid == 0) {
        float s[NE];
        #pragma unroll
        for (int e = 0; e < NE; e++)
            s[e] = part[0][e] + part[1][e] + part[2][e] + part[3][e] + gb[e];
        int amax = 0; float m = s[0];
        #pragma unroll
        for (int e = 1; e < NE; e++) if (s[e] > m) { m = s[e]; amax = e; }
        float denom = 0.f;
        #pragma unroll
        for (int e = 0; e < NE; e++) denom += expf(s[e] - m);
        gate_w[t] = 1.0f / denom;
        int pos = atomicAdd(&counts[amax], 1);
        tok_list[amax * NT + pos] = t;
    }
}

// ---- weight transpose + bf16 (vectorized): fp32 [e][R][C] -> bf16 [e][C][R] ----
__global__ __launch_bounds__(256) void transw_kernel(
    const float* __restrict__ s0, unsigned short* __restrict__ d0,
    const float* __restrict__ s1, unsigned short* __restrict__ d1,
    int R, int C)
{
    __shared__ unsigned int tile[64 * 33];   // packed bf16 pairs, +1 uint pad
    int e = blockIdx.z;
    int c0 = blockIdx.x * 64, r0 = blockIdx.y * 64;
    size_t off = (size_t)e * R * C;
    int tid = threadIdx.x;
    int rl = tid >> 4;                // 0..15
    int c4 = (tid & 15) * 4;          // 0..60
    int r4 = (tid & 15) * 4;
    #pragma unroll
    for (int p = 0; p < 2; ++p) {
        const float* src = (p ? s1 : s0) + off;
        unsigned short* dst = (p ? d1 : d0) + off;
        if (p) __syncthreads();
        #pragma unroll
        for (int jj = 0; jj < 4; ++jj) {
            int r = rl + 16 * jj;
            float4 v = *(const float4*)(src + (size_t)(r0 + r) * C + c0 + c4);
            tile[r * 33 + (c4 >> 1)]     = ((unsigned)f2bf(v.y) << 16) | f2bf(v.x);
            tile[r * 33 + (c4 >> 1) + 1] = ((unsigned)f2bf(v.w) << 16) | f2bf(v.z);
        }
        __syncthreads();
        #pragma unroll
        for (int ii = 0; ii < 4; ++ii) {
            int c = (tid >> 4) + 16 * ii;
            unsigned short o[4];
            #pragma unroll
            for (int j = 0; j < 4; ++j) {
                unsigned int u = tile[(r4 + j) * 33 + (c >> 1)];
                o[j] = (c & 1) ? (unsigned short)(u >> 16) : (unsigned short)(u & 0xFFFF);
            }
            *(ushort4*)(dst + (size_t)(c0 + c) * R + r0 + r4) = make_ushort4(o[0], o[1], o[2], o[3]);
        }
        if (p == 0) __syncthreads();
    }
}

// ---------------- stage 1: complex D->H -------------------------------------
// block 32M x 256N, FULL-K A (r,i) in LDS (staged once, zero K-loop barriers),
// B streamed global->VGPR per-lane dwordx4 frags. Wave = 32M x 64N (2 N-subtiles).
// A LDS swizzle on GLL source side: lane fetches chunk l^(row&7).
__global__ __launch_bounds__(256, 2) void moe1_kernel(
    const unsigned short* __restrict__ xbr, const unsigned short* __restrict__ xbi,
    const unsigned short* __restrict__ w1tr, const unsigned short* __restrict__ w1ti,
    const float* __restrict__ b1r, const float* __restrict__ b1i,
    const float* __restrict__ mod_b,
    const int* __restrict__ counts, const int* __restrict__ tok_list,
    unsigned short* __restrict__ hr, unsigned short* __restrict__ hi)
{
    int e = blockIdx.z;
    int n = counts[e];
    int mbase = blockIdx.y * 32;
    if (mbase >= n) return;
    int n0 = blockIdx.x * 256;
    int tid = threadIdx.x;
    int w = tid >> 6, l = tid & 63;
    int l31 = l & 31, half = l >> 5;

    __shared__ unsigned short sAr[32 * 512];   // 32 KB
    __shared__ unsigned short sAi[32 * 512];   // 32 KB
    __shared__ int toks[32];

    const int* tl = tok_list + e * NT;
    if (tid < 32) {
        int idx = mbase + tid;
        toks[tid] = tl[idx < n ? idx : n - 1];
    }
    __syncthreads();

    // stage A rows w*8..w*8+7 (r and i); one GLL = one full 512-elem row
    #pragma unroll
    for (int j = 0; j < 8; ++j) {
        int row = w * 8 + j;
        int tok = toks[row];
        int src = (l ^ (row & 7)) * 8;
        GLL(xbr + (size_t)tok * ND + src, &sAr[row * 512]);
        GLL(xbi + (size_t)tok * ND + src, &sAi[row * 512]);
    }
    __syncthreads();   // vmcnt(0) drain + barrier (once)

    size_t bbase = ((size_t)e * NH + n0 + w * 64 + l31) * ND + half * 8;
    const unsigned short* pBr0 = w1tr + bbase;
    const unsigned short* pBi0 = w1ti + bbase;
    const unsigned short* pBr1 = w1tr + bbase + (size_t)32 * ND;
    const unsigned short* pBi1 = w1ti + bbase + (size_t)32 * ND;

    int arow = l31 * 512;
    int axor = l31 & 7;

    f32x16 accr0 = {}, acci0 = {}, accr1 = {}, acci1 = {};

    #pragma unroll 4
    for (int ks = 0; ks < 32; ++ks) {
        int kc = ks * 2 + half;
        int ao = arow + ((kc ^ axor) * 8);
        short8 ar = lds8(sAr + ao);
        short8 ai = lds8(sAi + ao);
        short8 an = neg8(ai);
        short8 br0 = glb8(pBr0 + ks * 16);
        short8 bi0 = glb8(pBi0 + ks * 16);
        short8 br1 = glb8(pBr1 + ks * 16);
        short8 bi1 = glb8(pBi1 + ks * 16);
        accr0 = __builtin_amdgcn_mfma_f32_32x32x16_bf16(ar, br0, accr0, 0, 0, 0);
        accr0 = __builtin_amdgcn_mfma_f32_32x32x16_bf16(an, bi0, accr0, 0, 0, 0);
        acci0 = __builtin_amdgcn_mfma_f32_32x32x16_bf16(ar, bi0, acci0, 0, 0, 0);
        acci0 = __builtin_amdgcn_mfma_f32_32x32x16_bf16(ai, br0, acci0, 0, 0, 0);
        accr1 = __builtin_amdgcn_mfma_f32_32x32x16_bf16(ar, br1, accr1, 0, 0, 0);
        accr1 = __builtin_amdgcn_mfma_f32_32x32x16_bf16(an, bi1, accr1, 0, 0, 0);
        acci1 = __builtin_amdgcn_mfma_f32_32x32x16_bf16(ar, bi1, acci1, 0, 0, 0);
        acci1 = __builtin_amdgcn_mfma_f32_32x32x16_bf16(ai, br1, acci1, 0, 0, 0);
    }

    // epilogue: 32x32 C/D: col = lane&31, row = (reg&3) + 8*(reg>>2) + 4*half
    #pragma unroll
    for (int ns = 0; ns < 2; ++ns) {
        int col = n0 + w * 64 + ns * 32 + l31;
        float bre = b1r[(size_t)e * NH + col];
        float bie = b1i[(size_t)e * NH + col];
        float mbv = mod_b[(size_t)e * NH + col];
        const f32x16& cr = ns ? accr1 : accr0;
        const f32x16& ci = ns ? acci1 : acci0;
        #pragma unroll
        for (int reg = 0; reg < 16; ++reg) {
            int row = (reg & 3) + 8 * (reg >> 2) + 4 * half;
            if (mbase + row >= n) continue;
            int tok = toks[row];
            float vr = cr[reg] + bre;
            float vi = ci[reg] + bie;
            float a = sqrtf(vr * vr + vi * vi + 1e-10f);
            float sc = fmaxf(a + mbv, 0.0f) / (a + 1e-10f);
            hr[(size_t)tok * NH + col] = f2bf(vr * sc);
            hi[(size_t)tok * NH + col] = f2bf(vi * sc);
        }
    }
}

// ---------------- stage 2: complex H->D, split-K=4 --------------------------
// block 32M x 256N (ND=512 -> 2 col strips), K-slice 512 full in LDS,
// B streamed global->VGPR, atomic fp32 epilogue.
__global__ __launch_bounds__(256, 2) void moe2_kernel(
    const unsigned short* __restrict__ hr, const unsigned short* __restrict__ hi,
    const unsigned short* __restrict__ w2tr, const unsigned short* __restrict__ w2ti,
    const float* __restrict__ b2r, const float* __restrict__ b2i,
    const int* __restrict__ counts, const int* __restrict__ tok_list,
    const float* __restrict__ gate_w,
    float* __restrict__ out)
{
    int e = blockIdx.z >> 2;
    int ksl = blockIdx.z & 3;
    int n = counts[e];
    int mbase = blockIdx.y * 32;
    if (mbase >= n) return;
    int n0 = blockIdx.x * 256;
    int kbase = ksl * (NH / 4);
    int tid = threadIdx.x;
    int w = tid >> 6, l = tid & 63;
    int l31 = l & 31, half = l >> 5;

    __shared__ unsigned short sAr[32 * 512];
    __shared__ unsigned short sAi[32 * 512];
    __shared__ int toks[32];

    const int* tl = tok_list + e * NT;
    if (tid < 32) {
        int idx = mbase + tid;
        toks[tid] = tl[idx < n ? idx : n - 1];
    }
    __syncthreads();

    #pragma unroll
    for (int j = 0; j < 8; ++j) {
        int row = w * 8 + j;
        int tok = toks[row];
        int src = (l ^ (row & 7)) * 8;
        GLL(hr + (size_t)tok * NH + kbase + src, &sAr[row * 512]);
        GLL(hi + (size_t)tok * NH + kbase + src, &sAi[row * 512]);
    }
    __syncthreads();

    size_t bbase = ((size_t)e * ND + n0 + w * 64 + l31) * NH + kbase + half * 8;
    const unsigned short* pBr0 = w2tr + bbase;
    const unsigned short* pBi0 = w2ti + bbase;
    const unsigned short* pBr1 = w2tr + bbase + (size_t)32 * NH;
    const unsigned short* pBi1 = w2ti + bbase + (size_t)32 * NH;

    int arow = l31 * 512;
    int axor = l31 & 7;

    f32x16 accr0 = {}, acci0 = {}, accr1 = {}, acci1 = {};

    #pragma unroll 4
    for (int ks = 0; ks < 32; ++ks) {
        int kc = ks * 2 + half;
        int ao = arow + ((kc ^ axor) * 8);
        short8 ar = lds8(sAr + ao);
        short8 ai = lds8(sAi + ao);
        short8 an = neg8(ai);
        short8 br0 = glb8(pBr0 + ks * 16);
        short8 bi0 = glb8(pBi0 + ks * 16);
        short8 br1 = glb8(pBr1 + ks * 16);
        short8 bi1 = glb8(pBi1 + ks * 16);
        accr0 = __builtin_amdgcn_mfma_f32_32x32x16_bf16(ar, br0, accr0, 0, 0, 0);
        accr0 = __builtin_amdgcn_mfma_f32_32x32x16_bf16(an, bi0, accr0, 0, 0, 0);
        acci0 = __builtin_amdgcn_mfma_f32_32x32x16_bf16(ar, bi0, acci0, 0, 0, 0);
        acci0 = __builtin_amdgcn_mfma_f32_32x32x16_bf16(ai, br0, acci0, 0, 0, 0);
        accr1 = __builtin_amdgcn_mfma_f32_32x32x16_bf16(ar, br1, accr1, 0, 0, 0);
        accr1 = __builtin_amdgcn_mfma_f32_32x32x16_bf16(an, bi1, accr1, 0, 0, 0);
        acci1 = __builtin_amdgcn_mfma_f32_32x32x16_bf16(ar, bi1, acci1, 0, 0, 0);
        acci1 = __builtin_amdgcn_mfma_f32_32x32x16_bf16(ai, br1, acci1, 0, 0, 0);
    }

    #pragma unroll
    for (int ns = 0; ns < 2; ++ns) {
        int col = n0 + w * 64 + ns * 32 + l31;
        float bre = (ksl == 0) ? b2r[(size_t)e * ND + col] : 0.0f;
        float bie = (ksl == 0) ? b2i[(size_t)e * ND + col] : 0.0f;
        const f32x16& cr = ns ? accr1 : accr0;
        const f32x16& ci = ns ? acci1 : acci0;
        #pragma unroll
        for (int reg = 0; reg < 16; ++reg) {
            int row = (reg & 3) + 8 * (reg >> 2) + 4 * half;
            if (mbase + row >= n) continue;
            int tok = toks[row];
            float gw = gate_w[tok];
            atomicAdd(&out[(size_t)tok * ND + col], (cr[reg] + bre) * gw);
            atomicAdd(&out[(size_t)NT * ND + (size_t)tok * ND + col], (ci[reg] + bie) * gw);
        }
    }
}

extern "C" void kernel_launch(void* const* d_in, const int* in_sizes, int n_in,
                              void* d_out, int out_size, void* d_ws, size_t ws_size,
                              hipStream_t stream) {
    const float* xr   = (const float*)d_in[0];
    const float* xi   = (const float*)d_in[1];
    const float* gW   = (const float*)d_in[2];
    const float* gb   = (const float*)d_in[3];
    const float* W1r  = (const float*)d_in[4];
    const float* W1i  = (const float*)d_in[5];
    const float* b1r  = (const float*)d_in[6];
    const float* b1i  = (const float*)d_in[7];
    const float* modb = (const float*)d_in[8];
    const float* W2r  = (const float*)d_in[9];
    const float* W2i  = (const float*)d_in[10];
    const float* b2r  = (const float*)d_in[11];
    const float* b2i  = (const float*)d_in[12];
    float* out = (float*)d_out;

    char* ws = (char*)d_ws;
    int*   counts   = (int*)ws;                              // 256 B
    float* gate_w   = (float*)(ws + 256);                    // NT*4
    int*   tok_list = (int*)(ws + 256 + 8192);               // NE*NT*4
    size_t off = 256 + 8192 + (size_t)NE * NT * 4;
    unsigned short* xbr  = (unsigned short*)(ws + off); off += (size_t)NT * ND * 2;
    unsigned short* xbi  = (unsigned short*)(ws + off); off += (size_t)NT * ND * 2;
    unsigned short* w1tr = (unsigned short*)(ws + off); off += (size_t)NE * ND * NH * 2;
    unsigned short* w1ti = (unsigned short*)(ws + off); off += (size_t)NE * ND * NH * 2;
    unsigned short* w2tr = (unsigned short*)(ws + off); off += (size_t)NE * ND * NH * 2;
    unsigned short* w2ti = (unsigned short*)(ws + off); off += (size_t)NE * ND * NH * 2;
    unsigned short* h_r  = (unsigned short*)(ws + off); off += (size_t)NT * NH * 2;
    unsigned short* h_i  = (unsigned short*)(ws + off); off += (size_t)NT * NH * 2;

    hipMemsetAsync(counts, 0, 64 * sizeof(int), stream);
    hipMemsetAsync(out, 0, (size_t)out_size * sizeof(float), stream);
    gate_kernel<<<NT, 256, 0, stream>>>(xr, xi, gW, gb, gate_w, counts, tok_list, xbr, xbi);
    transw_kernel<<<dim3(NH / 64, ND / 64, NE), 256, 0, stream>>>(W1r, w1tr, W1i, w1ti, ND, NH);
    transw_kernel<<<dim3(ND / 64, NH / 64, NE), 256, 0, stream>>>(W2r, w2tr, W2i, w2ti, NH, ND);
    moe1_kernel<<<dim3(NH / 256, NT / 32, NE), 256, 0, stream>>>(
        xbr, xbi, w1tr, w1ti, b1r, b1i, modb, counts, tok_list, h_r, h_i);
    moe2_kernel<<<dim3(ND / 256, NT / 32, NE * 4), 256, 0, stream>>>(
        h_r, h_i, w2tr, w2ti, b2r, b2i, counts, tok_list, gate_w, out);
}